// Round 7
// baseline (156.079 us; speedup 1.0000x reference)
//
#include <hip/hip_runtime.h>
#include <math.h>

// R7: R6 geometry (8064B single LDS buffer -> cap-20 blocks/CU; 32 b/wave ->
// only 32 waves/CU to retire), with the pipeline unpoisoned:
//  - both tensors' 16 global_load_dwordx4 issued UP FRONT into regs (one
//    exposed latency window; targ lands under pass A's compute),
//  - peak live regs ~90 (targ 32 + py 33 + misc) < 128 cap -> no scratch
//    (R5/R6's 14MB WRITE_SIZE was spill; each spill = ~900cy in-chain),
//  - sched_barrier(0) only between pass-A ds_reads and targ ds_writes.
// Model (6-round fit): resident ~= 0.6*LDS-cap; time = retire/resident *
// lifetime. 32 / 12 * ~8.5us => predict 22-30us.
#define NPTS 21
#define FLB  63               // floats per batch per tensor
#define BPW  32               // batches per wave
#define THREADS 64            // one wave per block
#define TVEC (BPW * FLB / 4)  // 504 float4 per tensor chunk
#define FULLR (TVEC / 64)     // 7
#define TAILL (TVEC % 64)     // 56
#define KMAX 11               // points per lane (sub=0: 11, sub=1: 10)

__global__ __launch_bounds__(THREADS, 4)   // VGPR cap 128
void pa_mpjpe(const float* __restrict__ pred,
              const float* __restrict__ targ,
              float* __restrict__ ws,
              int B)
{
    __shared__ __align__(16) float sb[BPW * FLB];   // ONE 8064 B buffer

    const int lane = threadIdx.x & 63;
    const int b    = lane & (BPW - 1);        // batch within wave
    const int sub  = (lane >> 5) & 1;         // 0: even points, 1: odd points
    const int b0   = blockIdx.x * BPW;
    const int base = b * FLB;
    float4* w4 = (float4*)sb;

    const float4* gp = (const float4*)(pred + (size_t)b0 * FLB);
    const float4* gt = (const float4*)(targ + (size_t)b0 * FLB);

    // ---- issue ALL 16 global loads now; both tensors in flight ----
    float4 rp[FULLR + 1], rt[FULLR + 1];
    #pragma unroll
    for (int j = 0; j < FULLR; ++j) rp[j] = gp[j * 64 + lane];
    if (lane < TAILL)               rp[FULLR] = gp[FULLR * 64 + lane];
    #pragma unroll
    for (int j = 0; j < FULLR; ++j) rt[j] = gt[j * 64 + lane];
    if (lane < TAILL)               rt[FULLR] = gt[FULLR * 64 + lane];

    // ---- pred -> LDS (waits only on pred arrivals; rp dies here) ----
    #pragma unroll
    for (int j = 0; j < FULLR; ++j) w4[j * 64 + lane] = rp[j];
    if (lane < TAILL)               w4[FULLR * 64 + lane] = rp[FULLR];

    // ---- pass A: pred points -> py regs + Y moments (targ still in flight) ----
    float py0[KMAX], py1[KMAX], py2[KMAX];
    float sy0=0.f, sy1=0.f, sy2=0.f, syy=0.f;
    #pragma unroll
    for (int k = 0; k < KMAX; ++k) {
        const int n = 2 * k + sub;
        if (n < NPTS) {                        // only k=10,sub=1 masked
            const int o = base + 3 * n;
            float a = sb[o+0], e = sb[o+1], c = sb[o+2];
            py0[k] = a; py1[k] = e; py2[k] = c;
            sy0 += a; sy1 += e; sy2 += c;
            syy = fmaf(a, a, fmaf(e, e, fmaf(c, c, syy)));
        } else {
            py0[k] = 0.f; py1[k] = 0.f; py2[k] = 0.f;
        }
    }

    // pin order: targ ds_writes below must not rise above pass-A ds_reads.
    // (targ GLOBAL loads are already issued above -- nothing trapped.)
    __builtin_amdgcn_sched_barrier(0);

    // ---- targ -> same LDS buffer (data already/nearly arrived) ----
    #pragma unroll
    for (int j = 0; j < FULLR; ++j) w4[j * 64 + lane] = rt[j];
    if (lane < TAILL)               w4[FULLR * 64 + lane] = rt[FULLR];

    // ---- pass B1: X moments + raw cross-covariance (y from regs) ----
    float sx0=0.f, sx1=0.f, sx2=0.f;
    float m00=0,m01=0,m02=0, m10=0,m11=0,m12=0, m20=0,m21=0,m22=0;
    #pragma unroll
    for (int k = 0; k < KMAX; ++k) {
        const int n = 2 * k + sub;
        if (n < NPTS) {
            const int o = base + 3 * n;
            float u = sb[o+0], v = sb[o+1], x2 = sb[o+2];  // targ (X)
            float a = py0[k], e = py1[k], c = py2[k];      // pred (Y)
            sx0 += u; sx1 += v; sx2 += x2;
            m00 = fmaf(u,a,m00); m01 = fmaf(u,e,m01); m02 = fmaf(u,c,m02);
            m10 = fmaf(v,a,m10); m11 = fmaf(v,e,m11); m12 = fmaf(v,c,m12);
            m20 = fmaf(x2,a,m20); m21 = fmaf(x2,e,m21); m22 = fmaf(x2,c,m22);
        }
    }

    // ---- combine the 2 lanes of each batch (xor 32) ----
    #define COMB(v) { v += __shfl_xor(v, 32, 64); }
    COMB(sy0) COMB(sy1) COMB(sy2) COMB(syy)
    COMB(sx0) COMB(sx1) COMB(sx2)
    COMB(m00) COMB(m01) COMB(m02)
    COMB(m10) COMB(m11) COMB(m12)
    COMB(m20) COMB(m21) COMB(m22)
    #undef COMB

    const float invN = 1.0f / (float)NPTS;
    float mux0 = sx0*invN, mux1 = sx1*invN, mux2 = sx2*invN;
    float muy0 = sy0*invN, muy1 = sy1*invN, muy2 = sy2*invN;
    float ny2  = syy - (sy0*sy0 + sy1*sy1 + sy2*sy2) * invN;   // ||Y0||_F^2
    // centered cross-cov (rows: targ dims i, cols: pred dims j)
    float c00 = m00 - sx0*sy0*invN, c01 = m01 - sx0*sy1*invN, c02 = m02 - sx0*sy2*invN;
    float c10 = m10 - sx1*sy0*invN, c11 = m11 - sx1*sy1*invN, c12 = m12 - sx1*sy2*invN;
    float c20 = m20 - sx2*sy0*invN, c21 = m21 - sx2*sy1*invN, c22 = m22 - sx2*sy2*invN;

    // ---- orthogonal polar factor of A = Mc^T via det-scaled Newton ----
    float q00=c00, q01=c10, q02=c20,
          q10=c01, q11=c11, q12=c21,
          q20=c02, q21=c12, q22=c22;
    #pragma unroll
    for (int it = 0; it < 6; ++it) {
        float C00 = q11*q22 - q12*q21;
        float C01 = q12*q20 - q10*q22;
        float C02 = q10*q21 - q11*q20;
        float C10 = q02*q21 - q01*q22;
        float C11 = q00*q22 - q02*q20;
        float C12 = q01*q20 - q00*q21;
        float C20 = q01*q12 - q02*q11;
        float C21 = q02*q10 - q00*q12;
        float C22 = q00*q11 - q01*q10;
        float det = q00*C00 + q01*C01 + q02*C02;
        float ad  = fmaxf(fabsf(det), 1e-30f);
        float sdet = copysignf(ad, det);
        float g  = __expf(0.333333333f * __logf(ad));   // |det|^{1/3}
        float ha = 0.5f / g;                            // 0.5 * gamma
        float hb = 0.5f * g / sdet;                     // 0.5 * gamma^{-1} / det
        q00 = ha*q00 + hb*C00; q01 = ha*q01 + hb*C01; q02 = ha*q02 + hb*C02;
        q10 = ha*q10 + hb*C10; q11 = ha*q11 + hb*C11; q12 = ha*q12 + hb*C12;
        q20 = ha*q20 + hb*C20; q21 = ha*q21 + hb*C21; q22 = ha*q22 + hb*C22;
    }

    // tr(P) = <Q, A>_F with A = Mc^T (sum of singular values of Mc)
    float trP = q00*c00 + q01*c10 + q02*c20
              + q10*c01 + q11*c11 + q12*c21
              + q20*c02 + q21*c12 + q22*c22;
    float kk = trP / ny2;
    float r00=kk*q00, r01=kk*q01, r02=kk*q02;
    float r10=kk*q10, r11=kk*q11, r12=kk*q12;
    float r20=kk*q20, r21=kk*q21, r22=kk*q22;

    // ---- pass B2: per-joint error (targ still in LDS, pred from regs) ----
    float errsum = 0.0f;
    #pragma unroll
    for (int k = 0; k < KMAX; ++k) {
        const int n = 2 * k + sub;
        if (n < NPTS) {
            const int o = base + 3 * n;
            float xa = sb[o+0], xb = sb[o+1], xc = sb[o+2];
            float u = py0[k] - muy0, v = py1[k] - muy1, x2 = py2[k] - muy2;
            float z0 = fmaf(u, r00, fmaf(v, r10, fmaf(x2, r20, mux0))) - xa;
            float z1 = fmaf(u, r01, fmaf(v, r11, fmaf(x2, r21, mux1))) - xb;
            float z2 = fmaf(u, r02, fmaf(v, r12, fmaf(x2, r22, mux2))) - xc;
            errsum += sqrtf(fmaf(z0, z0, fmaf(z1, z1, z2*z2)));
        }
    }

    // ---- full-wave reduce (covers all 32 batches) -> one store per block ----
    #pragma unroll
    for (int off = 32; off > 0; off >>= 1) errsum += __shfl_down(errsum, off, 64);
    if (lane == 0) ws[blockIdx.x] = errsum;
}

// single block: reduce the per-block partials, write the final mean
__global__ __launch_bounds__(256)
void pa_reduce(const float* __restrict__ ws, float* __restrict__ out,
               int nblk, float inv_total)
{
    __shared__ float sw[4];
    float s = 0.0f;
    const float4* w4 = (const float4*)ws;
    const int n4 = nblk >> 2;                  // nblk divisible by 4
    for (int i = threadIdx.x; i < n4; i += 256) {
        float4 v = w4[i];
        s += (v.x + v.y) + (v.z + v.w);
    }
    #pragma unroll
    for (int off = 32; off > 0; off >>= 1) s += __shfl_down(s, off, 64);
    if ((threadIdx.x & 63) == 0) sw[threadIdx.x >> 6] = s;
    __syncthreads();
    if (threadIdx.x == 0)
        out[0] = (sw[0] + sw[1] + sw[2] + sw[3]) * inv_total;
}

extern "C" void kernel_launch(void* const* d_in, const int* in_sizes, int n_in,
                              void* d_out, int out_size, void* d_ws, size_t ws_size,
                              hipStream_t stream)
{
    const float* pred = (const float*)d_in[0];   // pred_kp3d   [B,21,3] f32
    const float* targ = (const float*)d_in[1];   // target_kp3d [B,21,3] f32
    float* out = (float*)d_out;
    float* ws  = (float*)d_ws;

    int B = in_sizes[0] / FLB;                   // 262144 (divisible by BPW)
    int grid = (B + BPW - 1) / BPW;              // 8192 blocks, 1 wave each
    float inv_total = 1.0f / ((float)B * (float)NPTS);

    pa_mpjpe<<<grid, THREADS, 0, stream>>>(pred, targ, ws, B);
    pa_reduce<<<1, 256, 0, stream>>>(ws, out, grid, inv_total);
}

// Round 8
// 154.682 us; speedup vs baseline: 1.0090x; 1.0090x over previous
//
#include <hip/hip_runtime.h>
#include <math.h>

// R8: break the residency*inflight invariant. Evidence: R1/R2/R3 all plateau
// at 21.4 batches/us/CU because one-shot LDS staging makes (resident waves) x
// (bytes in flight per wave) structurally constant; R4's DMA prefetch was
// nullified by the compiler's own vmcnt(0) before ds_read of DMA-written LDS;
// R5-R7's reg staging spilled BECAUSE float4 LOCAL ARRAYS lower to scratch
// (VGPR=52 yet WRITE=14.6MB -- not a budget spill, an SROA failure).
// Fix: NAMED float4 scalars for staging (no arrays), 2 chunks of 32 batches
// per wave, phases interleaved so <=16 float4 in flight and chunk n+1's
// loads fly under chunk n's compute. One 8064B LDS buffer reused by all 4
// stage phases (20 blk/CU cap). Retire halves to 16 waves/CU.
#define NPTS 21
#define FLB  63                 // floats per batch per tensor
#define CB   32                 // batches per chunk
#define BPW  (2 * CB)           // 64 batches per wave (2 chunks)
#define THREADS 64              // one wave per block
#define TVEC (CB * FLB / 4)     // 504 float4 per tensor-chunk
#define TAILL 56                // 504 - 7*64
#define KMAX 11                 // points per lane (sub=0: 11, sub=1: 10)

#define SBAR() __builtin_amdgcn_sched_barrier(0)

// 8 coalesced float4 loads into NAMED scalars (never an array -> never scratch)
#define LOAD8(v, g) do { \
    v##0 = (g)[0*64+lane]; v##1 = (g)[1*64+lane]; v##2 = (g)[2*64+lane]; \
    v##3 = (g)[3*64+lane]; v##4 = (g)[4*64+lane]; v##5 = (g)[5*64+lane]; \
    v##6 = (g)[6*64+lane]; if (lane < TAILL) v##7 = (g)[7*64+lane]; } while(0)

// matching LDS stores (compiler emits counted vmcnt before first use)
#define STORE8(v) do { \
    w4[0*64+lane] = v##0; w4[1*64+lane] = v##1; w4[2*64+lane] = v##2; \
    w4[3*64+lane] = v##3; w4[4*64+lane] = v##4; w4[5*64+lane] = v##5; \
    w4[6*64+lane] = v##6; if (lane < TAILL) w4[7*64+lane] = v##7; } while(0)

// pass A: pred points -> py regs + Y moments
#define PASSA() do { \
    sy0=0.f; sy1=0.f; sy2=0.f; syy=0.f; \
    _Pragma("unroll") \
    for (int k = 0; k < KMAX; ++k) { \
        const int n = 2*k + sub; \
        if (n < NPTS) { \
            const int o = base + 3*n; \
            float a = sb[o+0], e = sb[o+1], c = sb[o+2]; \
            py0[k]=a; py1[k]=e; py2[k]=c; \
            sy0+=a; sy1+=e; sy2+=c; \
            syy = fmaf(a,a,fmaf(e,e,fmaf(c,c,syy))); \
        } else { py0[k]=0.f; py1[k]=0.f; py2[k]=0.f; } \
    } } while(0)

#define COMB(v) { v += __shfl_xor(v, 32, 64); }

// pass B: X moments + cross-cov + Newton polar + error accumulation
#define PASSB() do { \
    float sx0=0.f, sx1=0.f, sx2=0.f; \
    float m00=0,m01=0,m02=0, m10=0,m11=0,m12=0, m20=0,m21=0,m22=0; \
    _Pragma("unroll") \
    for (int k = 0; k < KMAX; ++k) { \
        const int n = 2*k + sub; \
        if (n < NPTS) { \
            const int o = base + 3*n; \
            float u = sb[o+0], v = sb[o+1], x2 = sb[o+2]; \
            float a = py0[k], e = py1[k], c = py2[k]; \
            sx0+=u; sx1+=v; sx2+=x2; \
            m00=fmaf(u,a,m00); m01=fmaf(u,e,m01); m02=fmaf(u,c,m02); \
            m10=fmaf(v,a,m10); m11=fmaf(v,e,m11); m12=fmaf(v,c,m12); \
            m20=fmaf(x2,a,m20); m21=fmaf(x2,e,m21); m22=fmaf(x2,c,m22); \
        } \
    } \
    COMB(sy0) COMB(sy1) COMB(sy2) COMB(syy) \
    COMB(sx0) COMB(sx1) COMB(sx2) \
    COMB(m00) COMB(m01) COMB(m02) \
    COMB(m10) COMB(m11) COMB(m12) \
    COMB(m20) COMB(m21) COMB(m22) \
    const float invN = 1.0f / (float)NPTS; \
    float mux0=sx0*invN, mux1=sx1*invN, mux2=sx2*invN; \
    float muy0=sy0*invN, muy1=sy1*invN, muy2=sy2*invN; \
    float ny2 = syy - (sy0*sy0 + sy1*sy1 + sy2*sy2) * invN; \
    float c00=m00-sx0*sy0*invN, c01=m01-sx0*sy1*invN, c02=m02-sx0*sy2*invN; \
    float c10=m10-sx1*sy0*invN, c11=m11-sx1*sy1*invN, c12=m12-sx1*sy2*invN; \
    float c20=m20-sx2*sy0*invN, c21=m21-sx2*sy1*invN, c22=m22-sx2*sy2*invN; \
    float q00=c00, q01=c10, q02=c20, \
          q10=c01, q11=c11, q12=c21, \
          q20=c02, q21=c12, q22=c22; \
    _Pragma("unroll") \
    for (int it = 0; it < 6; ++it) { \
        float C00=q11*q22-q12*q21, C01=q12*q20-q10*q22, C02=q10*q21-q11*q20; \
        float C10=q02*q21-q01*q22, C11=q00*q22-q02*q20, C12=q01*q20-q00*q21; \
        float C20=q01*q12-q02*q11, C21=q02*q10-q00*q12, C22=q00*q11-q01*q10; \
        float det = q00*C00 + q01*C01 + q02*C02; \
        float ad  = fmaxf(fabsf(det), 1e-30f); \
        float sdet = copysignf(ad, det); \
        float g  = __expf(0.333333333f * __logf(ad)); \
        float ha = 0.5f / g; \
        float hb = 0.5f * g / sdet; \
        q00=ha*q00+hb*C00; q01=ha*q01+hb*C01; q02=ha*q02+hb*C02; \
        q10=ha*q10+hb*C10; q11=ha*q11+hb*C11; q12=ha*q12+hb*C12; \
        q20=ha*q20+hb*C20; q21=ha*q21+hb*C21; q22=ha*q22+hb*C22; \
    } \
    float trP = q00*c00 + q01*c10 + q02*c20 \
              + q10*c01 + q11*c11 + q12*c21 \
              + q20*c02 + q21*c12 + q22*c22; \
    float kk = trP / ny2; \
    float r00=kk*q00, r01=kk*q01, r02=kk*q02; \
    float r10=kk*q10, r11=kk*q11, r12=kk*q12; \
    float r20=kk*q20, r21=kk*q21, r22=kk*q22; \
    _Pragma("unroll") \
    for (int k = 0; k < KMAX; ++k) { \
        const int n = 2*k + sub; \
        if (n < NPTS) { \
            const int o = base + 3*n; \
            float xa = sb[o+0], xb = sb[o+1], xc = sb[o+2]; \
            float u = py0[k]-muy0, v = py1[k]-muy1, x2 = py2[k]-muy2; \
            float z0 = fmaf(u,r00,fmaf(v,r10,fmaf(x2,r20,mux0))) - xa; \
            float z1 = fmaf(u,r01,fmaf(v,r11,fmaf(x2,r21,mux1))) - xb; \
            float z2 = fmaf(u,r02,fmaf(v,r12,fmaf(x2,r22,mux2))) - xc; \
            errsum += sqrtf(fmaf(z0,z0,fmaf(z1,z1,z2*z2))); \
        } \
    } } while(0)

__global__ __launch_bounds__(THREADS, 3)   // VGPR cap ~170; need ~145
void pa_mpjpe(const float* __restrict__ pred,
              const float* __restrict__ targ,
              float* __restrict__ ws,
              int B)
{
    __shared__ __align__(16) float sb[CB * FLB];   // ONE 8064 B buffer
    float4* w4 = (float4*)sb;

    const int lane = threadIdx.x & 63;
    const int b    = lane & (CB - 1);
    const int sub  = (lane >> 5) & 1;
    const int base = b * FLB;
    const int b0   = blockIdx.x * BPW;

    const float4* gp0 = (const float4*)(pred + (size_t)b0 * FLB);
    const float4* gt0 = (const float4*)(targ + (size_t)b0 * FLB);
    const float4* gp1 = gp0 + TVEC;
    const float4* gt1 = gt0 + TVEC;

    float4 rp0, rp1, rp2, rp3, rp4, rp5, rp6, rp7 = make_float4(0,0,0,0);
    float4 rt0, rt1, rt2, rt3, rt4, rt5, rt6, rt7 = make_float4(0,0,0,0);
    float py0[KMAX], py1[KMAX], py2[KMAX];
    float sy0, sy1, sy2, syy;
    float errsum = 0.0f;

    // ---- phase 0: issue pred0 + targ0 (16 f4 in flight) ----
    LOAD8(rp, gp0);
    LOAD8(rt, gt0);
    SBAR();
    // ---- phase 1: pred0 -> LDS (counted vmcnt; rp dies) ----
    STORE8(rp);
    SBAR();
    // ---- phase 2: issue pred1 (targ0 + pred1 in flight) ----
    LOAD8(rp, gp1);
    SBAR();
    // ---- phase 3: pass A0 ----
    PASSA();
    SBAR();
    // ---- phase 4: targ0 -> LDS (arrived under pass A0) ----
    STORE8(rt);
    SBAR();
    // ---- phase 5: issue targ1 (pred1 + targ1 in flight) ----
    LOAD8(rt, gt1);
    SBAR();
    // ---- phase 6: pass B0 (targ1 flies under Newton) ----
    PASSB();
    SBAR();
    // ---- phase 7: pred1 -> LDS ----
    STORE8(rp);
    SBAR();
    // ---- phase 8: pass A1 ----
    PASSA();
    SBAR();
    // ---- phase 9: targ1 -> LDS ----
    STORE8(rt);
    SBAR();
    // ---- phase 10: pass B1 ----
    PASSB();

    // ---- full-wave reduce (64 batches) -> one store per block ----
    #pragma unroll
    for (int off = 32; off > 0; off >>= 1) errsum += __shfl_down(errsum, off, 64);
    if (lane == 0) ws[blockIdx.x] = errsum;
}

// single block: reduce the per-block partials, write the final mean
__global__ __launch_bounds__(256)
void pa_reduce(const float* __restrict__ ws, float* __restrict__ out,
               int nblk, float inv_total)
{
    __shared__ float sw[4];
    float s = 0.0f;
    const float4* w4 = (const float4*)ws;
    const int n4 = nblk >> 2;                  // nblk divisible by 4
    for (int i = threadIdx.x; i < n4; i += 256) {
        float4 v = w4[i];
        s += (v.x + v.y) + (v.z + v.w);
    }
    #pragma unroll
    for (int off = 32; off > 0; off >>= 1) s += __shfl_down(s, off, 64);
    if ((threadIdx.x & 63) == 0) sw[threadIdx.x >> 6] = s;
    __syncthreads();
    if (threadIdx.x == 0)
        out[0] = (sw[0] + sw[1] + sw[2] + sw[3]) * inv_total;
}

extern "C" void kernel_launch(void* const* d_in, const int* in_sizes, int n_in,
                              void* d_out, int out_size, void* d_ws, size_t ws_size,
                              hipStream_t stream)
{
    const float* pred = (const float*)d_in[0];   // pred_kp3d   [B,21,3] f32
    const float* targ = (const float*)d_in[1];   // target_kp3d [B,21,3] f32
    float* out = (float*)d_out;
    float* ws  = (float*)d_ws;

    int B = in_sizes[0] / FLB;                   // 262144 (divisible by BPW)
    int grid = (B + BPW - 1) / BPW;              // 4096 blocks, 1 wave each
    float inv_total = 1.0f / ((float)B * (float)NPTS);

    pa_mpjpe<<<grid, THREADS, 0, stream>>>(pred, targ, ws, B);
    pa_reduce<<<1, 256, 0, stream>>>(ws, out, grid, inv_total);
}

// Round 9
// 150.082 us; speedup vs baseline: 1.0400x; 1.0306x over previous
//
#include <hip/hip_runtime.h>
#include <math.h>

// R9: persistent-wave steady-state pipeline. Invariant so far: R1/R2/R3/R8
// all 47.5-50.5us (21 batches/us/CU) across 1.6x instr/batch, 4x batches/
// wave, 4x waves/block, DMA vs reg staging. VALU excluded (R1 vs R3), trans
// excluded, per-wave cost excluded (R8 vs R3). Surviving model: effective
// BW = avg outstanding bytes / latency; one-shot waves keep 16KB in flight
// only ~10% of lifetime. R8's 2-chunk version had no steady state (prologue
// = 50% of chunks, 16 restarts/CU). Fix: grid 2048 persistent blocks x 4
// chunks; per iter issue next chunk's 16 loads (named f4 scalars -- R8's
// no-spill fix) before passB so they fly under ~55% of the iteration;
// single 8064B LDS buffer reused pred->targ per chunk (R6 trick).
#define NPTS 21
#define FLB  63                 // floats per batch per tensor
#define CB   32                 // batches per chunk
#define THREADS 64              // one wave per block
#define TVEC (CB * FLB / 4)     // 504 float4 per tensor-chunk
#define TAILL 56                // 504 - 7*64
#define KMAX 11                 // points per lane (sub=0: 11, sub=1: 10)
#define GRID 2048               // 8 blocks/CU available; 4 chunks per block

#define SBAR() __builtin_amdgcn_sched_barrier(0)

// 8 coalesced float4 loads into NAMED scalars (arrays would lower to scratch)
#define LOAD8(v, g) do { \
    v##0 = (g)[0*64+lane]; v##1 = (g)[1*64+lane]; v##2 = (g)[2*64+lane]; \
    v##3 = (g)[3*64+lane]; v##4 = (g)[4*64+lane]; v##5 = (g)[5*64+lane]; \
    v##6 = (g)[6*64+lane]; if (lane < TAILL) v##7 = (g)[7*64+lane]; } while(0)

// matching LDS stores (compiler emits counted vmcnt before each first use)
#define STORE8(v) do { \
    w4[0*64+lane] = v##0; w4[1*64+lane] = v##1; w4[2*64+lane] = v##2; \
    w4[3*64+lane] = v##3; w4[4*64+lane] = v##4; w4[5*64+lane] = v##5; \
    w4[6*64+lane] = v##6; if (lane < TAILL) w4[7*64+lane] = v##7; } while(0)

// pass A: pred points -> py regs + Y moments
#define PASSA() do { \
    sy0=0.f; sy1=0.f; sy2=0.f; syy=0.f; \
    _Pragma("unroll") \
    for (int k = 0; k < KMAX; ++k) { \
        const int n = 2*k + sub; \
        if (n < NPTS) { \
            const int o = base + 3*n; \
            float a = sb[o+0], e = sb[o+1], c = sb[o+2]; \
            py0[k]=a; py1[k]=e; py2[k]=c; \
            sy0+=a; sy1+=e; sy2+=c; \
            syy = fmaf(a,a,fmaf(e,e,fmaf(c,c,syy))); \
        } else { py0[k]=0.f; py1[k]=0.f; py2[k]=0.f; } \
    } } while(0)

#define COMB(v) { v += __shfl_xor(v, 32, 64); }

// pass B: X moments + cross-cov + Newton polar + error accumulation
#define PASSB() do { \
    float sx0=0.f, sx1=0.f, sx2=0.f; \
    float m00=0,m01=0,m02=0, m10=0,m11=0,m12=0, m20=0,m21=0,m22=0; \
    _Pragma("unroll") \
    for (int k = 0; k < KMAX; ++k) { \
        const int n = 2*k + sub; \
        if (n < NPTS) { \
            const int o = base + 3*n; \
            float u = sb[o+0], v = sb[o+1], x2 = sb[o+2]; \
            float a = py0[k], e = py1[k], c = py2[k]; \
            sx0+=u; sx1+=v; sx2+=x2; \
            m00=fmaf(u,a,m00); m01=fmaf(u,e,m01); m02=fmaf(u,c,m02); \
            m10=fmaf(v,a,m10); m11=fmaf(v,e,m11); m12=fmaf(v,c,m12); \
            m20=fmaf(x2,a,m20); m21=fmaf(x2,e,m21); m22=fmaf(x2,c,m22); \
        } \
    } \
    COMB(sy0) COMB(sy1) COMB(sy2) COMB(syy) \
    COMB(sx0) COMB(sx1) COMB(sx2) \
    COMB(m00) COMB(m01) COMB(m02) \
    COMB(m10) COMB(m11) COMB(m12) \
    COMB(m20) COMB(m21) COMB(m22) \
    const float invN = 1.0f / (float)NPTS; \
    float mux0=sx0*invN, mux1=sx1*invN, mux2=sx2*invN; \
    float muy0=sy0*invN, muy1=sy1*invN, muy2=sy2*invN; \
    float ny2 = syy - (sy0*sy0 + sy1*sy1 + sy2*sy2) * invN; \
    float c00=m00-sx0*sy0*invN, c01=m01-sx0*sy1*invN, c02=m02-sx0*sy2*invN; \
    float c10=m10-sx1*sy0*invN, c11=m11-sx1*sy1*invN, c12=m12-sx1*sy2*invN; \
    float c20=m20-sx2*sy0*invN, c21=m21-sx2*sy1*invN, c22=m22-sx2*sy2*invN; \
    float q00=c00, q01=c10, q02=c20, \
          q10=c01, q11=c11, q12=c21, \
          q20=c02, q21=c12, q22=c22; \
    _Pragma("unroll") \
    for (int it = 0; it < 6; ++it) { \
        float C00=q11*q22-q12*q21, C01=q12*q20-q10*q22, C02=q10*q21-q11*q20; \
        float C10=q02*q21-q01*q22, C11=q00*q22-q02*q20, C12=q01*q20-q00*q21; \
        float C20=q01*q12-q02*q11, C21=q02*q10-q00*q12, C22=q00*q11-q01*q10; \
        float det = q00*C00 + q01*C01 + q02*C02; \
        float ad  = fmaxf(fabsf(det), 1e-30f); \
        float sdet = copysignf(ad, det); \
        float g  = __expf(0.333333333f * __logf(ad)); \
        float ha = 0.5f / g; \
        float hb = 0.5f * g / sdet; \
        q00=ha*q00+hb*C00; q01=ha*q01+hb*C01; q02=ha*q02+hb*C02; \
        q10=ha*q10+hb*C10; q11=ha*q11+hb*C11; q12=ha*q12+hb*C12; \
        q20=ha*q20+hb*C20; q21=ha*q21+hb*C21; q22=ha*q22+hb*C22; \
    } \
    float trP = q00*c00 + q01*c10 + q02*c20 \
              + q10*c01 + q11*c11 + q12*c21 \
              + q20*c02 + q21*c12 + q22*c22; \
    float kk = trP / ny2; \
    float r00=kk*q00, r01=kk*q01, r02=kk*q02; \
    float r10=kk*q10, r11=kk*q11, r12=kk*q12; \
    float r20=kk*q20, r21=kk*q21, r22=kk*q22; \
    _Pragma("unroll") \
    for (int k = 0; k < KMAX; ++k) { \
        const int n = 2*k + sub; \
        if (n < NPTS) { \
            const int o = base + 3*n; \
            float xa = sb[o+0], xb = sb[o+1], xc = sb[o+2]; \
            float u = py0[k]-muy0, v = py1[k]-muy1, x2 = py2[k]-muy2; \
            float z0 = fmaf(u,r00,fmaf(v,r10,fmaf(x2,r20,mux0))) - xa; \
            float z1 = fmaf(u,r01,fmaf(v,r11,fmaf(x2,r21,mux1))) - xb; \
            float z2 = fmaf(u,r02,fmaf(v,r12,fmaf(x2,r22,mux2))) - xc; \
            errsum += sqrtf(fmaf(z0,z0,fmaf(z1,z1,z2*z2))); \
        } \
    } } while(0)

__global__ __launch_bounds__(THREADS, 3)   // VGPR cap ~168; need ~140
void pa_mpjpe(const float* __restrict__ pred,
              const float* __restrict__ targ,
              float* __restrict__ ws,
              int B)
{
    __shared__ __align__(16) float sb[CB * FLB];   // ONE 8064 B buffer
    float4* w4 = (float4*)sb;

    const int lane = threadIdx.x & 63;
    const int b    = lane & (CB - 1);
    const int sub  = (lane >> 5) & 1;
    const int base = b * FLB;

    float4 rp0, rp1, rp2, rp3, rp4, rp5, rp6, rp7 = make_float4(0,0,0,0);
    float4 rt0, rt1, rt2, rt3, rt4, rt5, rt6, rt7 = make_float4(0,0,0,0);
    float py0[KMAX], py1[KMAX], py2[KMAX];
    float sy0, sy1, sy2, syy;
    float errsum = 0.0f;

    // ---- prologue: load chunk 0 (only fully-exposed latency window) ----
    {
        const float4* gp = (const float4*)(pred + (size_t)blockIdx.x * (CB*FLB));
        const float4* gt = (const float4*)(targ + (size_t)blockIdx.x * (CB*FLB));
        LOAD8(rp, gp);
        LOAD8(rt, gt);
    }
    SBAR();

    // ---- 4 chunks per block, steady-state pipeline ----
    #pragma unroll
    for (int i = 0; i < 4; ++i) {
        STORE8(rp);                 // pred(i) -> LDS (counted vmcnt; after
        SBAR();                     //   prev iter's B2 reads by alias order)
        PASSA();                    // pred -> py regs + Y moments
        SBAR();
        STORE8(rt);                 // targ(i) overwrites same buffer
        SBAR();
        if (i < 3) {                // issue chunk i+1's 16 loads NOW;
            const size_t c = (size_t)blockIdx.x + (size_t)(i + 1) * GRID;
            const float4* gp = (const float4*)(pred + c * (CB*FLB));
            const float4* gt = (const float4*)(targ + c * (CB*FLB));
            LOAD8(rp, gp);          //   they fly under passB (~55% of iter)
            LOAD8(rt, gt);
            SBAR();
        }
        PASSB();                    // X moments + M + Newton + error
        SBAR();
    }

    // ---- full-wave reduce (128 batches) -> one store per block ----
    #pragma unroll
    for (int off = 32; off > 0; off >>= 1) errsum += __shfl_down(errsum, off, 64);
    if (lane == 0) ws[blockIdx.x] = errsum;
}

// single block: reduce the per-block partials, write the final mean
__global__ __launch_bounds__(256)
void pa_reduce(const float* __restrict__ ws, float* __restrict__ out,
               int nblk, float inv_total)
{
    __shared__ float sw[4];
    float s = 0.0f;
    const float4* w4 = (const float4*)ws;
    const int n4 = nblk >> 2;                  // nblk divisible by 4
    for (int i = threadIdx.x; i < n4; i += 256) {
        float4 v = w4[i];
        s += (v.x + v.y) + (v.z + v.w);
    }
    #pragma unroll
    for (int off = 32; off > 0; off >>= 1) s += __shfl_down(s, off, 64);
    if ((threadIdx.x & 63) == 0) sw[threadIdx.x >> 6] = s;
    __syncthreads();
    if (threadIdx.x == 0)
        out[0] = (sw[0] + sw[1] + sw[2] + sw[3]) * inv_total;
}

extern "C" void kernel_launch(void* const* d_in, const int* in_sizes, int n_in,
                              void* d_out, int out_size, void* d_ws, size_t ws_size,
                              hipStream_t stream)
{
    const float* pred = (const float*)d_in[0];   // pred_kp3d   [B,21,3] f32
    const float* targ = (const float*)d_in[1];   // target_kp3d [B,21,3] f32
    float* out = (float*)d_out;
    float* ws  = (float*)d_ws;

    int B = in_sizes[0] / FLB;                   // 262144; 8192 chunks of 32
    int grid = GRID;                             // 2048 blocks x 4 chunks
    float inv_total = 1.0f / ((float)B * (float)NPTS);

    pa_mpjpe<<<grid, THREADS, 0, stream>>>(pred, targ, ws, B);
    pa_reduce<<<1, 256, 0, stream>>>(ws, out, grid, inv_total);
}